// Round 3
// baseline (14672.322 us; speedup 1.0000x reference)
//
#include <hip/hip_runtime.h>
#include <cstdint>
#include <cstddef>

#define T_SEQ 4096
#define HSZ   512
#define NGATE 2048   // 4*HSZ
#define DIN   1024
#define NB0   16     // layer-0 blocks per direction
#define HB0   32     // h-elements per layer-0 block (128 gate rows)
#define NB1   32     // layer-1 blocks per direction
#define HB1   16     // h-elements per layer-1 block (64 gate rows)
#define SLOTS 8      // exchange slots (epoch & 7)
#define CH    132    // skewed LDS chunk stride (128 + 4 floats)

typedef unsigned long long u64;
typedef unsigned int u32;

__device__ __forceinline__ u64 exld(const u64* p) {
  return __hip_atomic_load(p, __ATOMIC_RELAXED, __HIP_MEMORY_SCOPE_AGENT);
}
__device__ __forceinline__ void exst(u64* p, u64 v) {
  __hip_atomic_store(p, v, __ATOMIC_RELAXED, __HIP_MEMORY_SCOPE_AGENT);
}
__device__ __forceinline__ int pgld(const u32* p) {
  return (int)__hip_atomic_load(p, __ATOMIC_RELAXED, __HIP_MEMORY_SCOPE_AGENT);
}
__device__ __forceinline__ void pgst(u32* p, u32 v) {
  __hip_atomic_store(p, v, __ATOMIC_RELAXED, __HIP_MEMORY_SCOPE_AGENT);
}

__device__ __forceinline__ float fsigmoid(float x) { return 1.f / (1.f + __expf(-x)); }
__device__ __forceinline__ float ftanh(float x) {
  x = fminf(fmaxf(x, -10.f), 10.f);
  const float e = __expf(2.f * x);
  return (e - 1.f) / (e + 1.f);
}

// ---------------- init: zero exchange slots (epoch0 == h_0 == 0) + progress flags ----------------
__global__ void init_sync_kernel(u64* ex, u32* prog) {
  const int tid = blockIdx.x * blockDim.x + threadIdx.x;
  const int NEX = 2 * 2 * SLOTS * HSZ;           // ex0 + ex1
  for (int i = tid; i < NEX; i += gridDim.x * blockDim.x) exst(&ex[i], 0ull);
  if (tid < 2 * (NB0 + NB1)) pgst(&prog[tid], 0u);
}

// ---------------- fp32 GEMM with bias: P[t,r] = sum_k X[t,k]*W[r,k] + bi[r] + bh[r] ----------------
__global__ __launch_bounds__(256, 2)
void gemm_bias_kernel(const float* __restrict__ Xf, const float* __restrict__ Xb,
                      const float* __restrict__ Wf, const float* __restrict__ Wb,
                      const float* __restrict__ bif, const float* __restrict__ bhf,
                      const float* __restrict__ bib, const float* __restrict__ bhb,
                      float* __restrict__ Pf, float* __restrict__ Pb, int K)
{
  const int dir = blockIdx.z;
  const float* X  = dir ? Xb  : Xf;
  const float* W  = dir ? Wb  : Wf;
  const float* bi = dir ? bib : bif;
  const float* bh = dir ? bhb : bhf;
  float* P        = dir ? Pb  : Pf;

  const int m0 = blockIdx.x * 128;
  const int n0 = blockIdx.y * 128;
  const int tid = threadIdx.x;
  const int lr = tid >> 1;
  const int lk = (tid & 1) * 8;

  __shared__ float As[16*128];
  __shared__ float Bs[16*128];

  float acc[8][8];
  #pragma unroll
  for (int i = 0; i < 8; ++i)
    #pragma unroll
    for (int j = 0; j < 8; ++j) acc[i][j] = 0.f;

  for (int k0 = 0; k0 < K; k0 += 16) {
    const float4 a0 = *(const float4*)(X + (size_t)(m0+lr)*K + k0 + lk);
    const float4 a1 = *(const float4*)(X + (size_t)(m0+lr)*K + k0 + lk + 4);
    const float4 b0 = *(const float4*)(W + (size_t)(n0+lr)*K + k0 + lk);
    const float4 b1 = *(const float4*)(W + (size_t)(n0+lr)*K + k0 + lk + 4);
    __syncthreads();
    As[(lk+0)*128+lr]=a0.x; As[(lk+1)*128+lr]=a0.y; As[(lk+2)*128+lr]=a0.z; As[(lk+3)*128+lr]=a0.w;
    As[(lk+4)*128+lr]=a1.x; As[(lk+5)*128+lr]=a1.y; As[(lk+6)*128+lr]=a1.z; As[(lk+7)*128+lr]=a1.w;
    Bs[(lk+0)*128+lr]=b0.x; Bs[(lk+1)*128+lr]=b0.y; Bs[(lk+2)*128+lr]=b0.z; Bs[(lk+3)*128+lr]=b0.w;
    Bs[(lk+4)*128+lr]=b1.x; Bs[(lk+5)*128+lr]=b1.y; Bs[(lk+6)*128+lr]=b1.z; Bs[(lk+7)*128+lr]=b1.w;
    __syncthreads();
    #pragma unroll
    for (int kk = 0; kk < 16; ++kk) {
      const float4 A0 = *(const float4*)(As + kk*128 + (tid&15)*8);
      const float4 A1 = *(const float4*)(As + kk*128 + (tid&15)*8 + 4);
      const float4 B0 = *(const float4*)(Bs + kk*128 + (tid>>4)*8);
      const float4 B1 = *(const float4*)(Bs + kk*128 + (tid>>4)*8 + 4);
      const float av[8] = {A0.x,A0.y,A0.z,A0.w,A1.x,A1.y,A1.z,A1.w};
      const float bv[8] = {B0.x,B0.y,B0.z,B0.w,B1.x,B1.y,B1.z,B1.w};
      #pragma unroll
      for (int i = 0; i < 8; ++i)
        #pragma unroll
        for (int j = 0; j < 8; ++j) acc[i][j] += av[i]*bv[j];
    }
  }
  const int tm = m0 + (tid&15)*8;
  const int tn = n0 + (tid>>4)*8;
  #pragma unroll
  for (int i = 0; i < 8; ++i) {
    #pragma unroll
    for (int j = 0; j < 8; ++j) {
      const int n = tn + j;
      P[(size_t)(tm+i)*NGATE + n] = acc[i][j] + bi[n] + bh[n];
    }
  }
}

// ---------------- fused persistent recurrence ----------------
// blocks [0,32): L0 (16 fwd, 16 bwd)   [32,96): L1 (32 fwd, 32 bwd)
// Exchange: u64 packet (epoch<<32)|float_bits, 8 slots (epoch&7). Wave 0 (and wave 1
// for L1's h) polls with 8 independent latched loads per lane; other waves run
// overwrite guards; single barrier per step; gate gather via shfl_down (all 4 gates
// of an h-output live in one wave).
__global__ __launch_bounds__(512, 1)
void fused_recur_kernel(const float* __restrict__ Whh0_f, const float* __restrict__ Whh0_b,
                        const float* __restrict__ Wih1_f, const float* __restrict__ Whh1_f,
                        const float* __restrict__ bih1_f, const float* __restrict__ bhh1_f,
                        const float* __restrict__ Wih1_b, const float* __restrict__ Whh1_b,
                        const float* __restrict__ bih1_b, const float* __restrict__ bhh1_b,
                        const float* __restrict__ P_f, const float* __restrict__ P_b,
                        u64* ex0, u64* ex1, u32* prog0, u32* prog1,
                        float* __restrict__ out)
{
  const int bx   = blockIdx.x;
  const int tid  = threadIdx.x;
  const int lane = tid & 63;
  const int wv   = tid >> 6;

  __shared__ float xh[8*CH];   // up to 8 skewed 128-float chunks (L0 uses 4)

  if (bx < 2*NB0) {
    // ================= layer 0 =================
    const int dir = (bx >= NB0) ? 1 : 0;
    const int b   = bx - dir*NB0;
    const float* Whh = dir ? Whh0_b : Whh0_f;
    const float* P   = dir ? P_b    : P_f;
    u64* exS  = ex0 + (size_t)dir*SLOTS*HSZ;
    u32* prS  = prog0 + dir*NB0;
    u32* prL1 = prog1 + dir*NB1;

    const int rid = lane >> 2;          // 0..15 row-group
    const int cid = lane & 3;           // 0..3 col chunk (x128)
    const int g   = rid >> 2;           // gate 0..3
    const int jj  = rid & 3;            // output sub-index
    const int o   = wv*4 + jj;          // h-output 0..31 within block
    const int grow = g*HSZ + b*HB0 + o; // global gate row
    const bool owner = (cid == 0);
    const bool wr    = owner && (g == 0);   // lanes 0,4,8,12

    // weights: one row, 128 cols -> 32 float4 in VGPRs
    float4 w[32];
    {
      const float4* wp = (const float4*)(Whh + (size_t)grow*HSZ + cid*128);
      #pragma unroll
      for (int m = 0; m < 32; ++m) w[m] = wp[m];
    }

    float creg = 0.f;
    float pv = 0.f;
    if (owner) pv = P[(size_t)(dir ? (T_SEQ-1) : 0)*NGATE + grow];

    for (int t = 0; t < T_SEQ; ++t) {
      // prefetch next step's P (full step to land)
      float pvn = 0.f;
      if (owner) {
        const int tn = (t+1 < T_SEQ) ? t+1 : t;
        const int te = dir ? (T_SEQ-1-tn) : tn;
        pvn = P[(size_t)te*NGATE + grow];
      }
      if (wv == 0) {
        // poll h_t: 8 independent latched loads per lane
        const u64* sp = exS + (size_t)(t & 7)*HSZ + lane*8;
        u64 v[8]; u32 pend = 0xffu;
        do {
          u64 tmp[8];
          #pragma unroll
          for (int m = 0; m < 8; ++m) if (pend & (1u<<m)) tmp[m] = exld(sp+m);
          #pragma unroll
          for (int m = 0; m < 8; ++m)
            if ((pend & (1u<<m)) && (u32)(tmp[m] >> 32) == (u32)t) { v[m] = tmp[m]; pend &= ~(1u<<m); }
        } while (pend);
        float* dst = xh + (lane>>4)*CH + (lane&15)*8;
        #pragma unroll
        for (int m = 0; m < 8; ++m) dst[m] = __uint_as_float((u32)v[m]);
      } else if (wv == 1) {
        if (lane < NB0) { while (pgld(&prS[lane]) < t-6) {} }
      } else if (wv == 2) {
        if (lane < NB1) { while (pgld(&prL1[lane]) < t-6) {} }
      }
      __syncthreads();
      if (tid == 0) pgst(&prS[b], (u32)(t+1));

      const float4* h4 = (const float4*)(xh + cid*CH);
      float acc = 0.f;
      #pragma unroll
      for (int m = 0; m < 32; ++m) {
        const float4 hh = h4[m];
        acc += w[m].x*hh.x + w[m].y*hh.y + w[m].z*hh.z + w[m].w*hh.w;
      }
      acc += __shfl_xor(acc, 1);
      acc += __shfl_xor(acc, 2);
      if (owner) acc += pv;
      const float s1 = __shfl_down(acc, 16);
      const float s2 = __shfl_down(acc, 32);
      const float s3 = __shfl_down(acc, 48);
      if (wr) {
        const float i_s = fsigmoid(acc);
        const float f_s = fsigmoid(s1);
        const float gg  = ftanh(s2);
        const float o_s = fsigmoid(s3);
        creg = f_s*creg + i_s*gg;
        const float hnew = o_s*ftanh(creg);
        const int hidx = b*HB0 + o;
        const u64 pkt = ((u64)(u32)(t+1) << 32) | (u64)__float_as_uint(hnew);
        exst(exS + (size_t)((t+1) & 7)*HSZ + hidx, pkt);
        if (t == T_SEQ-1) {
          out[dir*HSZ + hidx]        = creg;   // cell_memories L0
          out[2048 + dir*HSZ + hidx] = hnew;   // hidden_states L0
        }
      }
      pv = pvn;
      __syncthreads();   // protect xh before next step's staging
    }
  } else {
    // ================= layer 1 =================
    const int r   = bx - 2*NB0;
    const int dir = (r >= NB1) ? 1 : 0;
    const int b   = r - dir*NB1;
    const float* Wih = dir ? Wih1_b : Wih1_f;
    const float* Whh = dir ? Whh1_b : Whh1_f;
    const float* bi  = dir ? bih1_b : bih1_f;
    const float* bh  = dir ? bhh1_b : bhh1_f;
    u64* exX = ex0 + (size_t)dir*SLOTS*HSZ;
    u64* exS = ex1 + (size_t)dir*SLOTS*HSZ;
    u32* prS = prog1 + dir*NB1;

    const int rid = lane >> 3;          // 0..7
    const int cid = lane & 7;           // 0..7 col chunk (x128 of 1024)
    const int g   = rid >> 1;           // gate
    const int jj  = rid & 1;
    const int o   = wv*2 + jj;          // h-output 0..15
    const int grow = g*HSZ + b*HB1 + o;
    const bool owner = (cid == 0);
    const bool wr    = owner && (g == 0);   // lanes 0, 8

    float4 w[32];
    {
      const float* wsrc = (cid < 4) ? (Wih + (size_t)grow*HSZ + cid*128)
                                    : (Whh + (size_t)grow*HSZ + (cid-4)*128);
      const float4* wp = (const float4*)wsrc;
      #pragma unroll
      for (int m = 0; m < 32; ++m) w[m] = wp[m];
    }
    float brow = 0.f;
    if (owner) brow = bi[grow] + bh[grow];

    float creg = 0.f;
    for (int t = 0; t < T_SEQ; ++t) {
      if (wv == 0) {
        // poll x_t = layer-0 epoch t+1
        const u64* sp = exX + (size_t)((t+1) & 7)*HSZ + lane*8;
        u64 v[8]; u32 pend = 0xffu;
        do {
          u64 tmp[8];
          #pragma unroll
          for (int m = 0; m < 8; ++m) if (pend & (1u<<m)) tmp[m] = exld(sp+m);
          #pragma unroll
          for (int m = 0; m < 8; ++m)
            if ((pend & (1u<<m)) && (u32)(tmp[m] >> 32) == (u32)(t+1)) { v[m] = tmp[m]; pend &= ~(1u<<m); }
        } while (pend);
        float* dst = xh + (lane>>4)*CH + (lane&15)*8;
        #pragma unroll
        for (int m = 0; m < 8; ++m) dst[m] = __uint_as_float((u32)v[m]);
      } else if (wv == 1) {
        // poll own h_t = epoch t
        const u64* sp = exS + (size_t)(t & 7)*HSZ + lane*8;
        u64 v[8]; u32 pend = 0xffu;
        do {
          u64 tmp[8];
          #pragma unroll
          for (int m = 0; m < 8; ++m) if (pend & (1u<<m)) tmp[m] = exld(sp+m);
          #pragma unroll
          for (int m = 0; m < 8; ++m)
            if ((pend & (1u<<m)) && (u32)(tmp[m] >> 32) == (u32)t) { v[m] = tmp[m]; pend &= ~(1u<<m); }
        } while (pend);
        float* dst = xh + (4 + (lane>>4))*CH + (lane&15)*8;
        #pragma unroll
        for (int m = 0; m < 8; ++m) dst[m] = __uint_as_float((u32)v[m]);
      } else if (wv == 2) {
        if (lane < NB1) { while (pgld(&prS[lane]) < t-6) {} }
      }
      __syncthreads();
      if (tid == 0) pgst(&prS[b], (u32)(t+1));

      const float4* v4 = (const float4*)(xh + cid*CH);
      float acc = 0.f;
      #pragma unroll
      for (int m = 0; m < 32; ++m) {
        const float4 hh = v4[m];
        acc += w[m].x*hh.x + w[m].y*hh.y + w[m].z*hh.z + w[m].w*hh.w;
      }
      acc += __shfl_xor(acc, 1);
      acc += __shfl_xor(acc, 2);
      acc += __shfl_xor(acc, 4);
      if (owner) acc += brow;
      const float s1 = __shfl_down(acc, 16);
      const float s2 = __shfl_down(acc, 32);
      const float s3 = __shfl_down(acc, 48);
      if (wr) {
        const float i_s = fsigmoid(acc);
        const float f_s = fsigmoid(s1);
        const float gg  = ftanh(s2);
        const float o_s = fsigmoid(s3);
        creg = f_s*creg + i_s*gg;
        const float hnew = o_s*ftanh(creg);
        const int hidx = b*HB1 + o;
        const u64 pkt = ((u64)(u32)(t+1) << 32) | (u64)__float_as_uint(hnew);
        exst(exS + (size_t)((t+1) & 7)*HSZ + hidx, pkt);
        const int trow = dir ? (T_SEQ-1-t) : t;
        out[4096 + (size_t)trow*1024 + dir*HSZ + hidx] = hnew;   // top-layer outputs
        if (t == T_SEQ-1) {
          out[1024 + dir*HSZ + hidx]        = creg;   // cell_memories L1
          out[2048 + 1024 + dir*HSZ + hidx] = hnew;   // hidden_states L1
        }
      }
      __syncthreads();   // protect xh before next step's staging
    }
  }
}

// ---------------- launch ----------------
extern "C" void kernel_launch(void* const* d_in, const int* in_sizes, int n_in,
                              void* d_out, int out_size, void* d_ws, size_t ws_size,
                              hipStream_t stream)
{
  const float* emb   = (const float*)d_in[0];
  const float* fWih0 = (const float*)d_in[1];
  const float* fWhh0 = (const float*)d_in[2];
  const float* fbih0 = (const float*)d_in[3];
  const float* fbhh0 = (const float*)d_in[4];
  const float* fWih1 = (const float*)d_in[5];
  const float* fWhh1 = (const float*)d_in[6];
  const float* fbih1 = (const float*)d_in[7];
  const float* fbhh1 = (const float*)d_in[8];
  const float* bWih0 = (const float*)d_in[9];
  const float* bWhh0 = (const float*)d_in[10];
  const float* bbih0 = (const float*)d_in[11];
  const float* bbhh0 = (const float*)d_in[12];
  const float* bWih1 = (const float*)d_in[13];
  const float* bWhh1 = (const float*)d_in[14];
  const float* bbih1 = (const float*)d_in[15];
  const float* bbhh1 = (const float*)d_in[16];
  float* out = (float*)d_out;

  // ws: P[2][4096][2048] fp32, ex0/ex1 [2][8][512] u64 each, prog flags
  float* P_f = (float*)d_ws;
  float* P_b = P_f + (size_t)T_SEQ*NGATE;
  u64*   ex0 = (u64*)(P_b + (size_t)T_SEQ*NGATE);
  u64*   ex1 = ex0 + (size_t)2*SLOTS*HSZ;
  u32*   prog0 = (u32*)(ex1 + (size_t)2*SLOTS*HSZ);
  u32*   prog1 = prog0 + 2*NB0;

  init_sync_kernel<<<16, 1024, 0, stream>>>(ex0, prog0);

  gemm_bias_kernel<<<dim3(32,16,2), 256, 0, stream>>>(
      emb, emb, fWih0, bWih0, fbih0, fbhh0, bbih0, bbhh0, P_f, P_b, DIN);

  fused_recur_kernel<<<96, 512, 0, stream>>>(
      fWhh0, bWhh0,
      fWih1, fWhh1, fbih1, fbhh1,
      bWih1, bWhh1, bbih1, bbhh1,
      P_f, P_b, ex0, ex1, prog0, prog1, out);
}

// Round 4
// 10249.376 us; speedup vs baseline: 1.4315x; 1.4315x over previous
//
#include <hip/hip_runtime.h>
#include <cstdint>
#include <cstddef>

#define T_SEQ 4096
#define HSZ   512
#define NGATE 2048   // 4*HSZ
#define DIN   1024
#define NB0   16     // layer-0 blocks per direction
#define HB0   32     // h-elements per layer-0 block (128 gate rows)
#define NB1   32     // layer-1 blocks per direction
#define HB1   16     // h-elements per layer-1 block (64 gate rows)
#define SLOTS 8      // exchange slots (epoch & 7)
#define CH    132    // skewed LDS chunk stride (128 + 4 floats) -> bank-disjoint b128 reads

typedef unsigned long long u64;
typedef unsigned int u32;

__device__ __forceinline__ u64 exld(const u64* p) {
  return __hip_atomic_load(p, __ATOMIC_RELAXED, __HIP_MEMORY_SCOPE_AGENT);
}
__device__ __forceinline__ void exst(u64* p, u64 v) {
  __hip_atomic_store(p, v, __ATOMIC_RELAXED, __HIP_MEMORY_SCOPE_AGENT);
}
__device__ __forceinline__ int pgld(const u32* p) {
  return (int)__hip_atomic_load(p, __ATOMIC_RELAXED, __HIP_MEMORY_SCOPE_AGENT);
}
__device__ __forceinline__ void pgst(u32* p, u32 v) {
  __hip_atomic_store(p, v, __ATOMIC_RELAXED, __HIP_MEMORY_SCOPE_AGENT);
}

__device__ __forceinline__ float fsigmoid(float x) { return 1.f / (1.f + __expf(-x)); }
__device__ __forceinline__ float ftanh(float x) {
  x = fminf(fmaxf(x, -10.f), 10.f);
  const float e = __expf(2.f * x);
  return (e - 1.f) / (e + 1.f);
}

// ---------------- init: zero exchange slots (epoch0 == h_0 == 0) + progress flags ----------------
__global__ void init_sync_kernel(u64* ex, u32* prog) {
  const int tid = blockIdx.x * blockDim.x + threadIdx.x;
  const int NEX = 2 * 2 * SLOTS * HSZ;           // ex0 + ex1
  for (int i = tid; i < NEX; i += gridDim.x * blockDim.x) exst(&ex[i], 0ull);
  if (tid < 2 * (NB0 + NB1)) pgst(&prog[tid], 0u);
}

// ---------------- fp32 GEMM with bias: P[t,r] = sum_k X[t,k]*W[r,k] + bi[r] + bh[r] ----------------
__global__ __launch_bounds__(256, 2)
void gemm_bias_kernel(const float* __restrict__ Xf, const float* __restrict__ Xb,
                      const float* __restrict__ Wf, const float* __restrict__ Wb,
                      const float* __restrict__ bif, const float* __restrict__ bhf,
                      const float* __restrict__ bib, const float* __restrict__ bhb,
                      float* __restrict__ Pf, float* __restrict__ Pb, int K)
{
  const int dir = blockIdx.z;
  const float* X  = dir ? Xb  : Xf;
  const float* W  = dir ? Wb  : Wf;
  const float* bi = dir ? bib : bif;
  const float* bh = dir ? bhb : bhf;
  float* P        = dir ? Pb  : Pf;

  const int m0 = blockIdx.x * 128;
  const int n0 = blockIdx.y * 128;
  const int tid = threadIdx.x;
  const int lr = tid >> 1;
  const int lk = (tid & 1) * 8;

  __shared__ float As[16*128];
  __shared__ float Bs[16*128];

  float acc[8][8];
  #pragma unroll
  for (int i = 0; i < 8; ++i)
    #pragma unroll
    for (int j = 0; j < 8; ++j) acc[i][j] = 0.f;

  for (int k0 = 0; k0 < K; k0 += 16) {
    const float4 a0 = *(const float4*)(X + (size_t)(m0+lr)*K + k0 + lk);
    const float4 a1 = *(const float4*)(X + (size_t)(m0+lr)*K + k0 + lk + 4);
    const float4 b0 = *(const float4*)(W + (size_t)(n0+lr)*K + k0 + lk);
    const float4 b1 = *(const float4*)(W + (size_t)(n0+lr)*K + k0 + lk + 4);
    __syncthreads();
    As[(lk+0)*128+lr]=a0.x; As[(lk+1)*128+lr]=a0.y; As[(lk+2)*128+lr]=a0.z; As[(lk+3)*128+lr]=a0.w;
    As[(lk+4)*128+lr]=a1.x; As[(lk+5)*128+lr]=a1.y; As[(lk+6)*128+lr]=a1.z; As[(lk+7)*128+lr]=a1.w;
    Bs[(lk+0)*128+lr]=b0.x; Bs[(lk+1)*128+lr]=b0.y; Bs[(lk+2)*128+lr]=b0.z; Bs[(lk+3)*128+lr]=b0.w;
    Bs[(lk+4)*128+lr]=b1.x; Bs[(lk+5)*128+lr]=b1.y; Bs[(lk+6)*128+lr]=b1.z; Bs[(lk+7)*128+lr]=b1.w;
    __syncthreads();
    #pragma unroll
    for (int kk = 0; kk < 16; ++kk) {
      const float4 A0 = *(const float4*)(As + kk*128 + (tid&15)*8);
      const float4 A1 = *(const float4*)(As + kk*128 + (tid&15)*8 + 4);
      const float4 B0 = *(const float4*)(Bs + kk*128 + (tid>>4)*8);
      const float4 B1 = *(const float4*)(Bs + kk*128 + (tid>>4)*8 + 4);
      const float av[8] = {A0.x,A0.y,A0.z,A0.w,A1.x,A1.y,A1.z,A1.w};
      const float bv[8] = {B0.x,B0.y,B0.z,B0.w,B1.x,B1.y,B1.z,B1.w};
      #pragma unroll
      for (int i = 0; i < 8; ++i)
        #pragma unroll
        for (int j = 0; j < 8; ++j) acc[i][j] += av[i]*bv[j];
    }
  }
  const int tm = m0 + (tid&15)*8;
  const int tn = n0 + (tid>>4)*8;
  #pragma unroll
  for (int i = 0; i < 8; ++i) {
    #pragma unroll
    for (int j = 0; j < 8; ++j) {
      const int n = tn + j;
      P[(size_t)(tm+i)*NGATE + n] = acc[i][j] + bi[n] + bh[n];
    }
  }
}

// ---------------- fused persistent recurrence ----------------
// blocks [0,32): L0 (16 fwd, 16 bwd)   [32,96): L1 (32 fwd, 32 bwd)
// Exchange: u64 packet (epoch<<32)|float_bits, 8 slots. Every thread polls its own
// value (single dependent load), stages stride-1 into double-buffered skewed LDS.
// ONE barrier per step; matvec reads are bank-disjoint ds_read_b128; gate partials
// gathered in-wave via shfl_down; gate math + publish spread across all 8 waves.
__global__ __launch_bounds__(512)
void fused_recur_kernel(const float* __restrict__ Whh0_f, const float* __restrict__ Whh0_b,
                        const float* __restrict__ Wih1_f, const float* __restrict__ Whh1_f,
                        const float* __restrict__ bih1_f, const float* __restrict__ bhh1_f,
                        const float* __restrict__ Wih1_b, const float* __restrict__ Whh1_b,
                        const float* __restrict__ bih1_b, const float* __restrict__ bhh1_b,
                        const float* __restrict__ P_f, const float* __restrict__ P_b,
                        u64* ex0, u64* ex1, u32* prog0, u32* prog1,
                        float* __restrict__ out)
{
  const int bx   = blockIdx.x;
  const int tid  = threadIdx.x;
  const int lane = tid & 63;
  const int wv   = tid >> 6;

  __shared__ float xh[2][8*CH];   // double-buffered skewed chunks (L0 uses 4/buf)

  if (bx < 2*NB0) {
    // ================= layer 0 =================
    const int dir = (bx >= NB0) ? 1 : 0;
    const int b   = bx - dir*NB0;
    const float* Whh = dir ? Whh0_b : Whh0_f;
    const float* P   = dir ? P_b    : P_f;
    u64* exS  = ex0 + (size_t)dir*SLOTS*HSZ;
    u32* prS  = prog0 + dir*NB0;
    u32* prL1 = prog1 + dir*NB1;

    const int cid = lane & 3;            // col chunk (x128)
    const int rid = lane >> 2;           // 0..15
    const int g   = rid >> 2;            // gate 0..3
    const int jj  = rid & 3;             // output sub-index
    const int o   = wv*4 + jj;           // h-output 0..31 within block
    const int grow = g*HSZ + b*HB0 + o;  // global gate row
    const bool owner = (cid == 0);
    const bool wr    = owner && (g == 0);   // lanes 0,4,8,12 of each wave

    float4 w[32];
    {
      const float4* wp = (const float4*)(Whh + (size_t)grow*HSZ + cid*128);
      #pragma unroll
      for (int m = 0; m < 32; ++m) w[m] = wp[m];
    }

    float creg = 0.f;
    float pv = 0.f;
    if (owner) pv = P[(size_t)(dir ? (T_SEQ-1) : 0)*NGATE + grow];

    for (int t = 0; t < T_SEQ; ++t) {
      // overwrite guards (lazy, off critical path with 8 slots)
      if (wv == 1 && lane < NB0) { while (pgld(&prS[lane])  < t-6) {} }
      if (wv == 2 && lane < NB1) { while (pgld(&prL1[lane]) < t-6) {} }
      // prefetch next step's P (full step to land)
      float pvn = 0.f;
      if (owner) {
        const int tn = (t+1 < T_SEQ) ? t+1 : t;
        const int te = dir ? (T_SEQ-1-tn) : tn;
        pvn = P[(size_t)te*NGATE + grow];
      }
      // poll own value of h_t (epoch t), stage stride-1 into buffer t&1
      {
        const u64* sp = exS + (size_t)(t & 7)*HSZ + tid;
        u64 v;
        do { v = exld(sp); } while ((u32)(v >> 32) != (u32)t);
        xh[t & 1][(tid>>7)*CH + (tid & 127)] = __uint_as_float((u32)v);
      }
      __syncthreads();
      if (tid == 0) pgst(&prS[b], (u32)(t+1));

      const float4* h4 = (const float4*)(&xh[t & 1][cid*CH]);
      float acc = 0.f;
      #pragma unroll
      for (int m = 0; m < 32; ++m) {
        const float4 hh = h4[m];
        acc += w[m].x*hh.x + w[m].y*hh.y + w[m].z*hh.z + w[m].w*hh.w;
      }
      acc += __shfl_xor(acc, 1);
      acc += __shfl_xor(acc, 2);
      if (owner) acc += pv;
      const float s1 = __shfl_down(acc, 16);
      const float s2 = __shfl_down(acc, 32);
      const float s3 = __shfl_down(acc, 48);
      if (wr) {
        const float i_s = fsigmoid(acc);
        const float f_s = fsigmoid(s1);
        const float gg  = ftanh(s2);
        const float o_s = fsigmoid(s3);
        creg = f_s*creg + i_s*gg;
        const float hnew = o_s*ftanh(creg);
        const int hidx = b*HB0 + o;
        const u64 pkt = ((u64)(u32)(t+1) << 32) | (u64)__float_as_uint(hnew);
        exst(exS + (size_t)((t+1) & 7)*HSZ + hidx, pkt);
        if (t == T_SEQ-1) {
          out[dir*HSZ + hidx]        = creg;   // cell_memories L0
          out[2048 + dir*HSZ + hidx] = hnew;   // hidden_states L0
        }
      }
      pv = pvn;
    }
  } else {
    // ================= layer 1 =================
    const int r   = bx - 2*NB0;
    const int dir = (r >= NB1) ? 1 : 0;
    const int b   = r - dir*NB1;
    const float* Wih = dir ? Wih1_b : Wih1_f;
    const float* Whh = dir ? Whh1_b : Whh1_f;
    const float* bi  = dir ? bih1_b : bih1_f;
    const float* bh  = dir ? bhh1_b : bhh1_f;
    u64* exX = ex0 + (size_t)dir*SLOTS*HSZ;
    u64* exS = ex1 + (size_t)dir*SLOTS*HSZ;
    u32* prS = prog1 + dir*NB1;

    const int cid = lane & 7;            // 0..7 col chunk (0-3: Wih/x, 4-7: Whh/h)
    const int rid = lane >> 3;           // 0..7
    const int g   = rid >> 1;            // gate
    const int jj  = rid & 1;
    const int o   = wv*2 + jj;           // h-output 0..15
    const int grow = g*HSZ + b*HB1 + o;
    const bool owner = (cid == 0);
    const bool wr    = owner && (g == 0);   // lanes 0, 8

    float4 w[32];
    {
      const float* wsrc = (cid < 4) ? (Wih + (size_t)grow*HSZ + cid*128)
                                    : (Whh + (size_t)grow*HSZ + (cid-4)*128);
      const float4* wp = (const float4*)wsrc;
      #pragma unroll
      for (int m = 0; m < 32; ++m) w[m] = wp[m];
    }
    float brow = 0.f;
    if (owner) brow = bi[grow] + bh[grow];

    float creg = 0.f;
    for (int t = 0; t < T_SEQ; ++t) {
      if (wv == 2 && lane < NB1) { while (pgld(&prS[lane]) < t-6) {} }
      // poll x_t (layer-0 publish, epoch t+1) and own h_t (epoch t); stage stride-1
      {
        const u64* px = exX + (size_t)((t+1) & 7)*HSZ + tid;
        const u64* ph = exS + (size_t)(t & 7)*HSZ + tid;
        float xv = 0.f, hv = 0.f;
        bool okx = false, okh = false;
        do {
          if (!okx) { u64 v = exld(px); if ((u32)(v >> 32) == (u32)(t+1)) { xv = __uint_as_float((u32)v); okx = true; } }
          if (!okh) { u64 v = exld(ph); if ((u32)(v >> 32) == (u32)t)     { hv = __uint_as_float((u32)v); okh = true; } }
        } while (!(okx && okh));
        xh[t & 1][(tid>>7)*CH + (tid & 127)]       = xv;   // chunks 0..3
        xh[t & 1][(4 + (tid>>7))*CH + (tid & 127)] = hv;   // chunks 4..7
      }
      __syncthreads();
      if (tid == 0) pgst(&prS[b], (u32)(t+1));

      const float4* v4 = (const float4*)(&xh[t & 1][cid*CH]);
      float acc = 0.f;
      #pragma unroll
      for (int m = 0; m < 32; ++m) {
        const float4 hh = v4[m];
        acc += w[m].x*hh.x + w[m].y*hh.y + w[m].z*hh.z + w[m].w*hh.w;
      }
      acc += __shfl_xor(acc, 1);
      acc += __shfl_xor(acc, 2);
      acc += __shfl_xor(acc, 4);
      if (owner) acc += brow;
      const float s1 = __shfl_down(acc, 16);
      const float s2 = __shfl_down(acc, 32);
      const float s3 = __shfl_down(acc, 48);
      if (wr) {
        const float i_s = fsigmoid(acc);
        const float f_s = fsigmoid(s1);
        const float gg  = ftanh(s2);
        const float o_s = fsigmoid(s3);
        creg = f_s*creg + i_s*gg;
        const float hnew = o_s*ftanh(creg);
        const int hidx = b*HB1 + o;
        const u64 pkt = ((u64)(u32)(t+1) << 32) | (u64)__float_as_uint(hnew);
        exst(exS + (size_t)((t+1) & 7)*HSZ + hidx, pkt);
        const int trow = dir ? (T_SEQ-1-t) : t;
        out[4096 + (size_t)trow*1024 + dir*HSZ + hidx] = hnew;   // top-layer outputs
        if (t == T_SEQ-1) {
          out[1024 + dir*HSZ + hidx]        = creg;   // cell_memories L1
          out[2048 + 1024 + dir*HSZ + hidx] = hnew;   // hidden_states L1
        }
      }
    }
  }
}

// ---------------- launch ----------------
extern "C" void kernel_launch(void* const* d_in, const int* in_sizes, int n_in,
                              void* d_out, int out_size, void* d_ws, size_t ws_size,
                              hipStream_t stream)
{
  const float* emb   = (const float*)d_in[0];
  const float* fWih0 = (const float*)d_in[1];
  const float* fWhh0 = (const float*)d_in[2];
  const float* fbih0 = (const float*)d_in[3];
  const float* fbhh0 = (const float*)d_in[4];
  const float* fWih1 = (const float*)d_in[5];
  const float* fWhh1 = (const float*)d_in[6];
  const float* fbih1 = (const float*)d_in[7];
  const float* fbhh1 = (const float*)d_in[8];
  const float* bWih0 = (const float*)d_in[9];
  const float* bWhh0 = (const float*)d_in[10];
  const float* bbih0 = (const float*)d_in[11];
  const float* bbhh0 = (const float*)d_in[12];
  const float* bWih1 = (const float*)d_in[13];
  const float* bWhh1 = (const float*)d_in[14];
  const float* bbih1 = (const float*)d_in[15];
  const float* bbhh1 = (const float*)d_in[16];
  float* out = (float*)d_out;

  // ws: P[2][4096][2048] fp32, ex0/ex1 [2][8][512] u64 each, prog flags
  float* P_f = (float*)d_ws;
  float* P_b = P_f + (size_t)T_SEQ*NGATE;
  u64*   ex0 = (u64*)(P_b + (size_t)T_SEQ*NGATE);
  u64*   ex1 = ex0 + (size_t)2*SLOTS*HSZ;
  u32*   prog0 = (u32*)(ex1 + (size_t)2*SLOTS*HSZ);
  u32*   prog1 = prog0 + 2*NB0;

  init_sync_kernel<<<16, 1024, 0, stream>>>(ex0, prog0);

  gemm_bias_kernel<<<dim3(32,16,2), 256, 0, stream>>>(
      emb, emb, fWih0, bWih0, fbih0, fbhh0, bbih0, bbhh0, P_f, P_b, DIN);

  fused_recur_kernel<<<96, 512, 0, stream>>>(
      fWhh0, bWhh0,
      fWih1, fWhh1, fbih1, fbhh1,
      bWih1, bWhh1, bbih1, bbhh1,
      P_f, P_b, ex0, ex1, prog0, prog1, out);
}

// Round 5
// 9919.714 us; speedup vs baseline: 1.4791x; 1.0332x over previous
//
#include <hip/hip_runtime.h>
#include <cstdint>
#include <cstddef>

#define T_SEQ 4096
#define HSZ   512
#define NGATE 2048   // 4*HSZ
#define DIN   1024
#define NB0   16     // layer-0 blocks per direction
#define HB0   32     // h-elements per layer-0 block (128 gate rows)
#define NB1   32     // layer-1 blocks per direction
#define HB1   16     // h-elements per layer-1 block (64 gate rows)
#define SLOTS 8      // exchange slots (epoch & 7)
#define CH    132    // skewed LDS chunk stride (128 + 4 floats) -> conflict-free broadcast reads

typedef unsigned long long u64;
typedef unsigned int u32;

__device__ __forceinline__ u64 exld(const u64* p) {
  return __hip_atomic_load(p, __ATOMIC_RELAXED, __HIP_MEMORY_SCOPE_AGENT);
}
__device__ __forceinline__ void exst(u64* p, u64 v) {
  __hip_atomic_store(p, v, __ATOMIC_RELAXED, __HIP_MEMORY_SCOPE_AGENT);
}
__device__ __forceinline__ int pgld(const u32* p) {
  return (int)__hip_atomic_load(p, __ATOMIC_RELAXED, __HIP_MEMORY_SCOPE_AGENT);
}
__device__ __forceinline__ void pgst(u32* p, u32 v) {
  __hip_atomic_store(p, v, __ATOMIC_RELAXED, __HIP_MEMORY_SCOPE_AGENT);
}

__device__ __forceinline__ float fsigmoid(float x) { return 1.f / (1.f + __expf(-x)); }
__device__ __forceinline__ float ftanh(float x) {
  x = fminf(fmaxf(x, -10.f), 10.f);
  const float e = __expf(2.f * x);
  return (e - 1.f) / (e + 1.f);
}

// ---------------- init: zero exchange slots (epoch0 == h_0 == 0) + progress flags ----------------
__global__ void init_sync_kernel(u64* ex, u32* prog) {
  const int tid = blockIdx.x * blockDim.x + threadIdx.x;
  const int NEX = 2 * 2 * SLOTS * HSZ;           // ex0 + ex1
  for (int i = tid; i < NEX; i += gridDim.x * blockDim.x) exst(&ex[i], 0ull);
  if (tid < 2 * (NB0 + NB1)) pgst(&prog[tid], 0u);
}

// ---------------- fp32 GEMM with bias: P[t,r] = sum_k X[t,k]*W[r,k] + bi[r] + bh[r] ----------------
__global__ __launch_bounds__(256, 2)
void gemm_bias_kernel(const float* __restrict__ Xf, const float* __restrict__ Xb,
                      const float* __restrict__ Wf, const float* __restrict__ Wb,
                      const float* __restrict__ bif, const float* __restrict__ bhf,
                      const float* __restrict__ bib, const float* __restrict__ bhb,
                      float* __restrict__ Pf, float* __restrict__ Pb, int K)
{
  const int dir = blockIdx.z;
  const float* X  = dir ? Xb  : Xf;
  const float* W  = dir ? Wb  : Wf;
  const float* bi = dir ? bib : bif;
  const float* bh = dir ? bhb : bhf;
  float* P        = dir ? Pb  : Pf;

  const int m0 = blockIdx.x * 128;
  const int n0 = blockIdx.y * 128;
  const int tid = threadIdx.x;
  const int lr = tid >> 1;
  const int lk = (tid & 1) * 8;

  __shared__ float As[16*128];
  __shared__ float Bs[16*128];

  float acc[8][8];
  #pragma unroll
  for (int i = 0; i < 8; ++i)
    #pragma unroll
    for (int j = 0; j < 8; ++j) acc[i][j] = 0.f;

  for (int k0 = 0; k0 < K; k0 += 16) {
    const float4 a0 = *(const float4*)(X + (size_t)(m0+lr)*K + k0 + lk);
    const float4 a1 = *(const float4*)(X + (size_t)(m0+lr)*K + k0 + lk + 4);
    const float4 b0 = *(const float4*)(W + (size_t)(n0+lr)*K + k0 + lk);
    const float4 b1 = *(const float4*)(W + (size_t)(n0+lr)*K + k0 + lk + 4);
    __syncthreads();
    As[(lk+0)*128+lr]=a0.x; As[(lk+1)*128+lr]=a0.y; As[(lk+2)*128+lr]=a0.z; As[(lk+3)*128+lr]=a0.w;
    As[(lk+4)*128+lr]=a1.x; As[(lk+5)*128+lr]=a1.y; As[(lk+6)*128+lr]=a1.z; As[(lk+7)*128+lr]=a1.w;
    Bs[(lk+0)*128+lr]=b0.x; Bs[(lk+1)*128+lr]=b0.y; Bs[(lk+2)*128+lr]=b0.z; Bs[(lk+3)*128+lr]=b0.w;
    Bs[(lk+4)*128+lr]=b1.x; Bs[(lk+5)*128+lr]=b1.y; Bs[(lk+6)*128+lr]=b1.z; Bs[(lk+7)*128+lr]=b1.w;
    __syncthreads();
    #pragma unroll
    for (int kk = 0; kk < 16; ++kk) {
      const float4 A0 = *(const float4*)(As + kk*128 + (tid&15)*8);
      const float4 A1 = *(const float4*)(As + kk*128 + (tid&15)*8 + 4);
      const float4 B0 = *(const float4*)(Bs + kk*128 + (tid>>4)*8);
      const float4 B1 = *(const float4*)(Bs + kk*128 + (tid>>4)*8 + 4);
      const float av[8] = {A0.x,A0.y,A0.z,A0.w,A1.x,A1.y,A1.z,A1.w};
      const float bv[8] = {B0.x,B0.y,B0.z,B0.w,B1.x,B1.y,B1.z,B1.w};
      #pragma unroll
      for (int i = 0; i < 8; ++i)
        #pragma unroll
        for (int j = 0; j < 8; ++j) acc[i][j] += av[i]*bv[j];
    }
  }
  const int tm = m0 + (tid&15)*8;
  const int tn = n0 + (tid>>4)*8;
  #pragma unroll
  for (int i = 0; i < 8; ++i) {
    #pragma unroll
    for (int j = 0; j < 8; ++j) {
      const int n = tn + j;
      P[(size_t)(tm+i)*NGATE + n] = acc[i][j] + bi[n] + bh[n];
    }
  }
}

// ---------------- fused persistent recurrence (R2 skeleton + micro-opts) ----------------
// blocks [0,32): L0 (16 fwd, 16 bwd)   [32,96): L1 (32 fwd, 32 bwd)
// Exchange: u64 packet (epoch<<32)|float_bits, 8 slots. Per-thread single-value poll,
// stride-1 staging into skewed LDS. Gate math + publish CONCENTRATED in wave 0 so the
// whole block's h leaves as ONE coalesced store (readers gate on the last producer store).
// Matvec uses 4 accumulators; P prefetched a full step ahead; L1 outputs staged in LDS
// and flushed as exact 64B lines (off critical path, after publish).
__global__ __launch_bounds__(512)
void fused_recur_kernel(const float* __restrict__ Whh0_f, const float* __restrict__ Whh0_b,
                        const float* __restrict__ Wih1_f, const float* __restrict__ Whh1_f,
                        const float* __restrict__ bih1_f, const float* __restrict__ bhh1_f,
                        const float* __restrict__ Wih1_b, const float* __restrict__ Whh1_b,
                        const float* __restrict__ bih1_b, const float* __restrict__ bhh1_b,
                        const float* __restrict__ P_f, const float* __restrict__ P_b,
                        u64* ex0, u64* ex1, u32* prog0, u32* prog1,
                        float* __restrict__ out)
{
  const int bx   = blockIdx.x;
  const int tid  = threadIdx.x;
  const int lane = tid & 63;
  const int wv   = tid >> 6;

  __shared__ float xh[8*CH];     // skewed chunks (L0 uses 4)
  __shared__ float gates[128];
  __shared__ float outst[16];    // L1 per-step output staging (one 64B line)

  if (bx < 2*NB0) {
    // ================= layer 0 =================
    const int dir = (bx >= NB0) ? 1 : 0;
    const int b   = bx - dir*NB0;
    const float* Whh = dir ? Whh0_b : Whh0_f;
    const float* P   = dir ? P_b    : P_f;
    u64* exS  = ex0 + (size_t)dir*SLOTS*HSZ;
    u32* prS  = prog0 + dir*NB0;
    u32* prL1 = prog1 + dir*NB1;

    const int cc        = lane >> 4;             // col chunk 0..3
    const int row_local = wv*16 + (lane & 15);   // 0..127
    const int g    = row_local >> 5;
    const int k    = row_local & 31;
    const int grow = g*HSZ + b*HB0 + k;
    const bool owner = (lane >> 4) == 0;         // 16 lanes/wave: row-sum owners

    float4 w[32];
    {
      const float4* wp = (const float4*)(Whh + (size_t)grow*HSZ + cc*128);
      #pragma unroll
      for (int m = 0; m < 32; ++m) w[m] = wp[m];
    }

    float creg = 0.f;
    float pv = 0.f;
    if (owner) pv = P[(size_t)(dir ? (T_SEQ-1) : 0)*NGATE + grow];

    for (int t = 0; t < T_SEQ; ++t) {
      // lazy overwrite guards (well off critical path with 8 slots)
      if (wv == 1 && lane < NB0) { while (pgld(&prS[lane])  < t-6) {} }
      if (wv == 2 && lane < NB1) { while (pgld(&prL1[lane]) < t-6) {} }
      // prefetch next step's P (register-carried, full step to land)
      float pvn = 0.f;
      if (owner) {
        const int tn = (t+1 < T_SEQ) ? t+1 : t;
        const int te = dir ? (T_SEQ-1-tn) : tn;
        pvn = P[(size_t)te*NGATE + grow];
      }
      // poll own value of h_t (epoch t), stage stride-1
      {
        const u64* sp = exS + (size_t)(t & 7)*HSZ + tid;
        u64 v;
        do { v = exld(sp); } while ((u32)(v >> 32) != (u32)t);
        xh[(tid>>7)*CH + (tid & 127)] = __uint_as_float((u32)v);
      }
      __syncthreads();
      if (tid == 0) pgst(&prS[b], (u32)(t+1));

      // matvec: 4 independent accumulators (short dep chains)
      const float4* h4 = (const float4*)(xh + cc*CH);
      float a0 = 0.f, a1 = 0.f, a2 = 0.f, a3 = 0.f;
      #pragma unroll
      for (int m = 0; m < 32; m += 4) {
        const float4 h0 = h4[m+0], h1 = h4[m+1], h2 = h4[m+2], h3 = h4[m+3];
        a0 += w[m+0].x*h0.x + w[m+0].y*h0.y + w[m+0].z*h0.z + w[m+0].w*h0.w;
        a1 += w[m+1].x*h1.x + w[m+1].y*h1.y + w[m+1].z*h1.z + w[m+1].w*h1.w;
        a2 += w[m+2].x*h2.x + w[m+2].y*h2.y + w[m+2].z*h2.z + w[m+2].w*h2.w;
        a3 += w[m+3].x*h3.x + w[m+3].y*h3.y + w[m+3].z*h3.z + w[m+3].w*h3.w;
      }
      float acc = (a0 + a1) + (a2 + a3);
      acc += __shfl_xor(acc, 16);
      acc += __shfl_xor(acc, 32);
      if (owner) gates[row_local] = acc + pv;
      __syncthreads();
      if (tid < HB0) {   // wave 0: gate math + ONE coalesced publish
        const float ig = gates[tid], fg = gates[32+tid], gg = gates[64+tid], og = gates[96+tid];
        const float i_s = fsigmoid(ig);
        const float f_s = fsigmoid(fg);
        const float o_s = fsigmoid(og);
        creg = f_s*creg + i_s*ftanh(gg);
        const float hnew = o_s*ftanh(creg);
        const int hidx = b*HB0 + tid;
        const u64 pkt = ((u64)(u32)(t+1) << 32) | (u64)__float_as_uint(hnew);
        exst(exS + (size_t)((t+1) & 7)*HSZ + hidx, pkt);
        if (t == T_SEQ-1) {
          out[dir*HSZ + hidx]        = creg;   // cell_memories L0
          out[2048 + dir*HSZ + hidx] = hnew;   // hidden_states L0
        }
      }
      pv = pvn;
    }
  } else {
    // ================= layer 1 =================
    const int r   = bx - 2*NB0;
    const int dir = (r >= NB1) ? 1 : 0;
    const int b   = r - dir*NB1;
    const float* Wih = dir ? Wih1_b : Wih1_f;
    const float* Whh = dir ? Whh1_b : Whh1_f;
    const float* bi  = dir ? bih1_b : bih1_f;
    const float* bh  = dir ? bhh1_b : bhh1_f;
    u64* exX = ex0 + (size_t)dir*SLOTS*HSZ;
    u64* exS = ex1 + (size_t)dir*SLOTS*HSZ;
    u32* prS = prog1 + dir*NB1;

    const int cc        = lane >> 3;             // 0..7 col chunk (0-3: Wih/x, 4-7: Whh/h)
    const int row_local = wv*8 + (lane & 7);     // 0..63
    const int g    = row_local >> 4;
    const int k    = row_local & 15;
    const int grow = g*HSZ + b*HB1 + k;
    const bool owner = (lane >> 3) == 0;         // 8 lanes/wave

    float4 w[32];
    {
      const float* wsrc = (cc < 4) ? (Wih + (size_t)grow*HSZ + cc*128)
                                   : (Whh + (size_t)grow*HSZ + (cc-4)*128);
      const float4* wp = (const float4*)wsrc;
      #pragma unroll
      for (int m = 0; m < 32; ++m) w[m] = wp[m];
    }
    float brow = 0.f;
    if (owner) brow = bi[grow] + bh[grow];

    float creg = 0.f;
    for (int t = 0; t < T_SEQ; ++t) {
      if (wv == 2 && lane < NB1) { while (pgld(&prS[lane]) < t-6) {} }
      // poll x_t (L0 epoch t+1) and own h_t (epoch t) concurrently; stage stride-1
      {
        const u64* px = exX + (size_t)((t+1) & 7)*HSZ + tid;
        const u64* ph = exS + (size_t)(t & 7)*HSZ + tid;
        float xv = 0.f, hv = 0.f;
        bool okx = false, okh = false;
        do {
          if (!okx) { u64 v = exld(px); if ((u32)(v >> 32) == (u32)(t+1)) { xv = __uint_as_float((u32)v); okx = true; } }
          if (!okh) { u64 v = exld(ph); if ((u32)(v >> 32) == (u32)t)     { hv = __uint_as_float((u32)v); okh = true; } }
        } while (!(okx && okh));
        xh[(tid>>7)*CH + (tid & 127)]       = xv;   // chunks 0..3
        xh[(4 + (tid>>7))*CH + (tid & 127)] = hv;   // chunks 4..7
      }
      __syncthreads();
      if (tid == 0) pgst(&prS[b], (u32)(t+1));

      const float4* v4 = (const float4*)(xh + cc*CH);
      float a0 = 0.f, a1 = 0.f, a2 = 0.f, a3 = 0.f;
      #pragma unroll
      for (int m = 0; m < 32; m += 4) {
        const float4 h0 = v4[m+0], h1 = v4[m+1], h2 = v4[m+2], h3 = v4[m+3];
        a0 += w[m+0].x*h0.x + w[m+0].y*h0.y + w[m+0].z*h0.z + w[m+0].w*h0.w;
        a1 += w[m+1].x*h1.x + w[m+1].y*h1.y + w[m+1].z*h1.z + w[m+1].w*h1.w;
        a2 += w[m+2].x*h2.x + w[m+2].y*h2.y + w[m+2].z*h2.z + w[m+2].w*h2.w;
        a3 += w[m+3].x*h3.x + w[m+3].y*h3.y + w[m+3].z*h3.z + w[m+3].w*h3.w;
      }
      float acc = (a0 + a1) + (a2 + a3);
      acc += __shfl_xor(acc, 8);
      acc += __shfl_xor(acc, 16);
      acc += __shfl_xor(acc, 32);
      if (owner) gates[row_local] = acc + brow;
      __syncthreads();
      if (wv == 0) {   // wave 0: gate math, ONE coalesced publish, then coalesced out-flush
        float hnew = 0.f;
        if (lane < HB1) {
          const float ig = gates[lane], fg = gates[16+lane], gg = gates[32+lane], og = gates[48+lane];
          const float i_s = fsigmoid(ig);
          const float f_s = fsigmoid(fg);
          const float o_s = fsigmoid(og);
          creg = f_s*creg + i_s*ftanh(gg);
          hnew = o_s*ftanh(creg);
          const int hidx = b*HB1 + lane;
          const u64 pkt = ((u64)(u32)(t+1) << 32) | (u64)__float_as_uint(hnew);
          exst(exS + (size_t)((t+1) & 7)*HSZ + hidx, pkt);   // critical publish first
          outst[lane] = hnew;
          if (t == T_SEQ-1) {
            out[1024 + dir*HSZ + hidx]        = creg;   // cell_memories L1
            out[2048 + 1024 + dir*HSZ + hidx] = hnew;   // hidden_states L1
          }
        }
        asm volatile("s_waitcnt lgkmcnt(0)" ::: "memory");   // outst visible within wave 0
        if (lane < 4) {   // 4 lanes x float4 = one exact 64B line
          const float4 v = *(const float4*)(outst + lane*4);
          const int trow = dir ? (T_SEQ-1-t) : t;
          *(float4*)(out + 4096 + (size_t)trow*1024 + dir*HSZ + b*HB1 + lane*4) = v;
        }
      }
    }
  }
}

// ---------------- launch ----------------
extern "C" void kernel_launch(void* const* d_in, const int* in_sizes, int n_in,
                              void* d_out, int out_size, void* d_ws, size_t ws_size,
                              hipStream_t stream)
{
  const float* emb   = (const float*)d_in[0];
  const float* fWih0 = (const float*)d_in[1];
  const float* fWhh0 = (const float*)d_in[2];
  const float* fbih0 = (const float*)d_in[3];
  const float* fbhh0 = (const float*)d_in[4];
  const float* fWih1 = (const float*)d_in[5];
  const float* fWhh1 = (const float*)d_in[6];
  const float* fbih1 = (const float*)d_in[7];
  const float* fbhh1 = (const float*)d_in[8];
  const float* bWih0 = (const float*)d_in[9];
  const float* bWhh0 = (const float*)d_in[10];
  const float* bbih0 = (const float*)d_in[11];
  const float* bbhh0 = (const float*)d_in[12];
  const float* bWih1 = (const float*)d_in[13];
  const float* bWhh1 = (const float*)d_in[14];
  const float* bbih1 = (const float*)d_in[15];
  const float* bbhh1 = (const float*)d_in[16];
  float* out = (float*)d_out;

  // ws: P[2][4096][2048] fp32, ex0/ex1 [2][8][512] u64 each, prog flags
  float* P_f = (float*)d_ws;
  float* P_b = P_f + (size_t)T_SEQ*NGATE;
  u64*   ex0 = (u64*)(P_b + (size_t)T_SEQ*NGATE);
  u64*   ex1 = ex0 + (size_t)2*SLOTS*HSZ;
  u32*   prog0 = (u32*)(ex1 + (size_t)2*SLOTS*HSZ);
  u32*   prog1 = prog0 + 2*NB0;

  init_sync_kernel<<<16, 1024, 0, stream>>>(ex0, prog0);

  gemm_bias_kernel<<<dim3(32,16,2), 256, 0, stream>>>(
      emb, emb, fWih0, bWih0, fbih0, fbhh0, bbih0, bbhh0, P_f, P_b, DIN);

  fused_recur_kernel<<<96, 512, 0, stream>>>(
      fWhh0, bWhh0,
      fWih1, fWhh1, fbih1, fbhh1,
      bWih1, bWhh1, bbih1, bbhh1,
      P_f, P_b, ex0, ex1, prog0, prog1, out);
}